// Round 1
// 1066.681 us; speedup vs baseline: 1.6497x; 1.6497x over previous
//
#include <hip/hip_runtime.h>
#include <hip/hip_bf16.h>

// Swin block: B=32,H=112,W=112,C=96, heads=3, ws=7, shift=3. NTOK=32*256*49
#define NTOK 401408

typedef __attribute__((ext_vector_type(8))) short s8v;   // 8 x bf16 bits
typedef __attribute__((ext_vector_type(4))) float f4v;   // MFMA C/D frag

__device__ __forceinline__ float bs2f(short s) {
  unsigned u = ((unsigned)(unsigned short)s) << 16;
  float f; __builtin_memcpy(&f, &u, 4); return f;
}
__device__ __forceinline__ short f2bs(float f) {
  __hip_bfloat16 b = __float2bfloat16(f);
  return *reinterpret_cast<short*>(&b);
}
__device__ __forceinline__ s8v ld8(const short* p) { return *(const s8v*)p; }
// region id on the SHIFTED image for the attention mask
__device__ __forceinline__ int rgn(int a) { return (a < 105) ? 0 : ((a < 109) ? 1 : 2); }

// in-wave LDS fence: DS pipe is in-order per wave; lgkmcnt(0) makes writes
// visible to same-wave cross-lane reads. sched_barrier stops hipcc hoisting
// non-memory ops (rule: MFMA can cross inline-asm waits).
__device__ __forceinline__ void wave_lds_fence() {
  asm volatile("s_waitcnt lgkmcnt(0)" ::: "memory");
  __builtin_amdgcn_sched_barrier(0);
}

// ---- dual-dtype accessors: logical float array stored as bf16 or fp32 ----
__device__ __forceinline__ void ld8d(const void* base, size_t elem, int isb, float* o) {
  if (isb) {
    s8v v = *(const s8v*)((const short*)base + elem);
    #pragma unroll
    for (int j = 0; j < 8; j++) o[j] = bs2f(v[j]);
  } else {
    const float* f = (const float*)base + elem;
    float4 a = *(const float4*)f;
    float4 b = *(const float4*)(f + 4);
    o[0]=a.x; o[1]=a.y; o[2]=a.z; o[3]=a.w; o[4]=b.x; o[5]=b.y; o[6]=b.z; o[7]=b.w;
  }
}
__device__ __forceinline__ void st8d(void* base, size_t elem, int isb, const float* v) {
  if (isb) {
    s8v o;
    #pragma unroll
    for (int j = 0; j < 8; j++) o[j] = f2bs(v[j]);
    *(s8v*)((short*)base + elem) = o;
  } else {
    float* f = (float*)base + elem;
    float4 a = {v[0], v[1], v[2], v[3]};
    float4 b = {v[4], v[5], v[6], v[7]};
    *(float4*)f = a;
    *(float4*)(f + 4) = b;
  }
}
__device__ __forceinline__ float lddf(const void* base, size_t elem, int isb) {
  return isb ? bs2f(((const short*)base)[elem]) : ((const float*)base)[elem];
}
__device__ __forceinline__ void stdf(void* base, size_t elem, int isb, float v) {
  if (isb) ((short*)base)[elem] = f2bs(v); else ((float*)base)[elem] = v;
}

// ---- bf16 weight-table element offsets inside d_ws (after 8-elem flag slot) ----
#define OQW   0
#define OQB   27648
#define OPW   27936
#define OPB   37152
#define ORPB  37248
#define ON1W  37760
#define ON1B  37856
#define ON2W  37952
#define ON2B  38048
#define OF1W  38144
#define OF1B  75008
#define OF2W  75392
#define OF2B  112256

// ============ prepass: detect input dtype, convert weights to bf16 ==========
// 64 blocks: each block re-detects dtype locally (same 4KB, L2 broadcast),
// converts a grid-strided slice. Was 1 block = ~serial latency chain.
__global__ __launch_bounds__(256) void k_detect_convert(
    const void* x,
    const void* qw, const void* qb, const void* pw, const void* pb, const void* rpb,
    const void* n1w, const void* n1b, const void* n2w, const void* n2b,
    const void* f1w, const void* f1b, const void* f2w, const void* f2b,
    int* flag, short* wb)
{
  __shared__ int cnt_sh;
  if (threadIdx.x == 0) cnt_sh = 0;
  __syncthreads();
  const unsigned* xw = (const unsigned*)x;
  int c = 0;
  for (int i = threadIdx.x; i < 1024; i += 256) {
    unsigned e = (xw[i] >> 7) & 0xFFu;      // exponent field of LOW bf16 half
    if (e >= 0x70u && e <= 0x8Fu) c++;
  }
  atomicAdd(&cnt_sh, c);
  __syncthreads();
  const int isb = (cnt_sh > 512) ? 1 : 0;   // bf16 data: ~1024; fp32 mantissa noise: ~128
  if (blockIdx.x == 0 && threadIdx.x == 0) *flag = isb;

  const void* srcs[13] = {qw, qb, pw, pb, rpb, n1w, n1b, n2w, n2b, f1w, f1b, f2w, f2b};
  const int   ns[13]   = {27648, 288, 9216, 96, 507, 96, 96, 96, 96, 36864, 384, 36864, 96};
  const int   offs[13] = {OQW, OQB, OPW, OPB, ORPB, ON1W, ON1B, ON2W, ON2B, OF1W, OF1B, OF2W, OF2B};
  const int gtid = blockIdx.x * 256 + threadIdx.x;
  for (int a = 0; a < 13; a++) {
    const void* s = srcs[a];
    for (int i = gtid; i < ns[a]; i += 64 * 256)
      wb[offs[a] + i] = f2bs(isb ? bs2f(((const short*)s)[i]) : ((const float*)s)[i]);
  }
}

// ================= Kernel A: LN1 + shift/window + QKV + attn + proj =========
// one block per window (8192 blocks), 192 threads = 3 waves, wave h = head h.
// LDS 44544 B. LDS layout (shorts):
//   wave h Q/K slab at h*5120: Q [64][40] then K [64][40]  (5120 total)
//   P [64][72] = 4608 overlays the OWN wave's Q/K slab -> per-wave reuse
//   V at 15360 + h*2304: [32][72]; reused as O [64][32]
// Only the proj phase reads other waves' LDS -> single __syncthreads().
__global__ __launch_bounds__(192, 3) void k_attn_fused(
    const void* __restrict__ xg, const short* __restrict__ wb,
    const int* __restrict__ flag, void* __restrict__ xrout)
{
  __shared__ __align__(16) short smem[22272];

  const int isb = *flag;
  const int h = threadIdx.x >> 6;
  const int lane = threadIdx.x & 63;
  const int quad = lane >> 4, l15 = lane & 15;
  const int wi = blockIdx.x;
  const int bb = wi >> 8, wp = wi & 255, wh = wp >> 4, ww = wp & 15;

  short* Qh = smem + h * 5120;            // [64][40]
  short* Kh = Qh + 2560;                  // [64][40]
  short* Ph = smem + h * 5120;            // [64][72] overlays own Q/K
  short* Vh = smem + 15360 + h * 2304;    // [32][72]  (then O as [64][32])

  // LN gamma/beta for this lane's 24 channels
  float gwv[3][8], gbv[3][8];
  #pragma unroll
  for (int kc = 0; kc < 3; kc++) {
    s8v g = ld8(wb + ON1W + kc * 32 + quad * 8);
    s8v t = ld8(wb + ON1B + kc * 32 + quad * 8);
    #pragma unroll
    for (int j = 0; j < 8; j++) { gwv[kc][j] = bs2f(g[j]); gbv[kc][j] = bs2f(t[j]); }
  }

  // gather + LN1 into A-fragments (row = token, k = channel)
  s8v af[4][3];
  #pragma unroll
  for (int rt = 0; rt < 4; rt++) {
    int n = rt * 16 + l15; if (n > 48) n = 48;            // pad rows: dup row 48
    int ii = n / 7, jj = n - ii * 7;
    int hi = wh * 7 + ii + 3; if (hi >= 112) hi -= 112;   // roll(-3) gather
    int wj = ww * 7 + jj + 3; if (wj >= 112) wj -= 112;
    size_t rowoff = ((size_t)bb * 12544 + hi * 112 + wj) * 96;
    float v[3][8]; float sm = 0.f, sq = 0.f;
    #pragma unroll
    for (int kc = 0; kc < 3; kc++) {
      ld8d(xg, rowoff + kc * 32 + quad * 8, isb, v[kc]);
      #pragma unroll
      for (int j = 0; j < 8; j++) { sm += v[kc][j]; sq += v[kc][j] * v[kc][j]; }
    }
    sm += __shfl_xor(sm, 16); sm += __shfl_xor(sm, 32);   // reduce across quads
    sq += __shfl_xor(sq, 16); sq += __shfl_xor(sq, 32);
    float mean = sm * (1.f / 96.f);
    float var  = sq * (1.f / 96.f) - mean * mean;
    float rstd = rsqrtf(var + 1e-5f);
    #pragma unroll
    for (int kc = 0; kc < 3; kc++) {
      s8v o;
      #pragma unroll
      for (int j = 0; j < 8; j++) o[j] = f2bs((v[kc][j] - mean) * rstd * gwv[kc][j] + gbv[kc][j]);
      af[rt][kc] = o;
    }
  }

  // QKV gemm: wave h computes head h's Q,K,V (2 col-tiles each)
  const float qscale = 0.1767766952966369f;  // 32^-0.5 folded into Q
  #pragma unroll
  for (int s = 0; s < 3; s++) {
    #pragma unroll
    for (int nt = 0; nt < 2; nt++) {
      int col = s * 96 + h * 32 + nt * 16 + l15;
      const short* wrow = wb + OQW + (size_t)col * 96;
      s8v b0 = ld8(wrow + quad * 8), b1 = ld8(wrow + 32 + quad * 8), b2 = ld8(wrow + 64 + quad * 8);
      float bias = bs2f(wb[OQB + col]);
      #pragma unroll
      for (int rt = 0; rt < 4; rt++) {
        f4v acc = {0.f, 0.f, 0.f, 0.f};
        acc = __builtin_amdgcn_mfma_f32_16x16x32_bf16(af[rt][0], b0, acc, 0, 0, 0);
        acc = __builtin_amdgcn_mfma_f32_16x16x32_bf16(af[rt][1], b1, acc, 0, 0, 0);
        acc = __builtin_amdgcn_mfma_f32_16x16x32_bf16(af[rt][2], b2, acc, 0, 0, 0);
        #pragma unroll
        for (int r = 0; r < 4; r++) {
          int tok = rt * 16 + quad * 4 + r;          // C-layout: row=quad*4+r, col=l15
          float val = acc[r] + bias;
          int cc = nt * 16 + l15;
          if (s == 0)      Qh[tok * 40 + cc] = f2bs(val * qscale);
          else if (s == 1) Kh[tok * 40 + cc] = f2bs(val);
          else             Vh[cc * 72 + tok] = f2bs(val);   // transposed
        }
      }
    }
  }
  wave_lds_fence();   // (was barrier #0) Q/K/V stores are per-wave slabs

  s8v qa[4], kb[4], vf[2][2];
  #pragma unroll
  for (int t = 0; t < 4; t++) {
    qa[t] = *(const s8v*)&Qh[(t * 16 + l15) * 40 + quad * 8];
    kb[t] = *(const s8v*)&Kh[(t * 16 + l15) * 40 + quad * 8];
  }
  #pragma unroll
  for (int nt = 0; nt < 2; nt++)
    #pragma unroll
    for (int kc = 0; kc < 2; kc++)
      vf[nt][kc] = *(const s8v*)&Vh[(nt * 16 + l15) * 72 + kc * 32 + quad * 8];

  // bias/mask geometry per key column
  int crid[4], ci[4], cj[4]; bool cv[4];
  #pragma unroll
  for (int nt = 0; nt < 4; nt++) {
    int col = nt * 16 + l15;
    cv[nt] = (col < 49);
    int ki = col / 7, kj = col - ki * 7;
    ci[nt] = ki; cj[nt] = kj;
    crid[nt] = rgn(wh * 7 + ki) * 3 + rgn(ww * 7 + kj);
  }

  // QK^T + softmax per row-tile (sc held only one tile at a time: 16 regs not 64).
  // P overlays OWN wave's Q/K: qa/kb/vf already in registers; DS pipe is
  // in-order per wave so P writes land after the fragment reads. No barrier.
  #pragma unroll
  for (int rt = 0; rt < 4; rt++) {
    f4v sc4[4];
    #pragma unroll
    for (int nt = 0; nt < 4; nt++) {
      f4v z = {0.f, 0.f, 0.f, 0.f};
      sc4[nt] = __builtin_amdgcn_mfma_f32_16x16x32_bf16(qa[rt], kb[nt], z, 0, 0, 0);
    }
    #pragma unroll
    for (int rr = 0; rr < 4; rr++) {
      int row = rt * 16 + quad * 4 + rr;
      bool vr = (row < 49);
      int ri = row / 7, rj = row - ri * 7;
      int rrid = rgn(wh * 7 + ri) * 3 + rgn(ww * 7 + rj);
      float vals[4];
      float m = -1e30f;
      #pragma unroll
      for (int nt = 0; nt < 4; nt++) {
        float sv;
        if (vr && cv[nt]) {
          int bidx = (ri - ci[nt] + 6) * 13 + (rj - cj[nt] + 6);
          float bias = bs2f(wb[ORPB + bidx * 3 + h]);
          sv = sc4[nt][rr] + bias + ((rrid == crid[nt]) ? 0.f : -100.f);
        } else {
          sv = vr ? -1e30f : 0.f;
        }
        vals[nt] = sv;
        m = fmaxf(m, sv);
      }
      #pragma unroll
      for (int o = 1; o < 16; o <<= 1) m = fmaxf(m, __shfl_xor(m, o));
      float sum = 0.f;
      #pragma unroll
      for (int nt = 0; nt < 4; nt++) { vals[nt] = __expf(vals[nt] - m); sum += vals[nt]; }
      #pragma unroll
      for (int o = 1; o < 16; o <<= 1) sum += __shfl_xor(sum, o);
      float inv = 1.f / sum;
      #pragma unroll
      for (int nt = 0; nt < 4; nt++)
        Ph[row * 72 + nt * 16 + l15] = f2bs(vals[nt] * inv);
    }
  }
  wave_lds_fence();   // (was barrier #2) P per-wave

  // PV
  s8v pf[4][2];
  #pragma unroll
  for (int rt = 0; rt < 4; rt++)
    #pragma unroll
    for (int kc = 0; kc < 2; kc++)
      pf[rt][kc] = *(const s8v*)&Ph[(rt * 16 + l15) * 72 + kc * 32 + quad * 8];
  short* Oh = Vh;   // [64][32], own wave's region
  #pragma unroll
  for (int rt = 0; rt < 4; rt++) {
    #pragma unroll
    for (int nt = 0; nt < 2; nt++) {
      f4v acc = {0.f, 0.f, 0.f, 0.f};
      acc = __builtin_amdgcn_mfma_f32_16x16x32_bf16(pf[rt][0], vf[nt][0], acc, 0, 0, 0);
      acc = __builtin_amdgcn_mfma_f32_16x16x32_bf16(pf[rt][1], vf[nt][1], acc, 0, 0, 0);
      #pragma unroll
      for (int r = 0; r < 4; r++) {
        int tok = rt * 16 + quad * 4 + r;
        Oh[tok * 32 + nt * 16 + l15] = f2bs(acc[r]);
      }
    }
  }
  __syncthreads();   // the ONE true cross-wave barrier: proj reads all heads' O

  // proj: A = O (k = 3 heads x 32), wave h computes out cols h*32..+31
  s8v of[4][3];
  #pragma unroll
  for (int rt = 0; rt < 4; rt++)
    #pragma unroll
    for (int kc = 0; kc < 3; kc++)
      of[rt][kc] = *(const s8v*)&smem[15360 + kc * 2304 + (rt * 16 + l15) * 32 + quad * 8];
  #pragma unroll
  for (int nt = 0; nt < 2; nt++) {
    int col = h * 32 + nt * 16 + l15;
    const short* wrow = wb + OPW + (size_t)col * 96;
    s8v b0 = ld8(wrow + quad * 8), b1 = ld8(wrow + 32 + quad * 8), b2 = ld8(wrow + 64 + quad * 8);
    float bias = bs2f(wb[OPB + col]);
    #pragma unroll
    for (int rt = 0; rt < 4; rt++) {
      f4v acc = {0.f, 0.f, 0.f, 0.f};
      acc = __builtin_amdgcn_mfma_f32_16x16x32_bf16(of[rt][0], b0, acc, 0, 0, 0);
      acc = __builtin_amdgcn_mfma_f32_16x16x32_bf16(of[rt][1], b1, acc, 0, 0, 0);
      acc = __builtin_amdgcn_mfma_f32_16x16x32_bf16(of[rt][2], b2, acc, 0, 0, 0);
      #pragma unroll
      for (int r = 0; r < 4; r++) {
        int tok = rt * 16 + quad * 4 + r;
        if (tok < 49) {
          int ii = tok / 7, jj = tok - ii * 7;
          int hi = wh * 7 + ii + 3; if (hi >= 112) hi -= 112;  // reverse + roll(+3)
          int wj = ww * 7 + jj + 3; if (wj >= 112) wj -= 112;
          size_t dest = ((size_t)bb * 12544 + hi * 112 + wj) * 96 + col;
          stdf(xrout, dest, isb, acc[r] + bias);
        }
      }
    }
  }
}

// ================= Kernel B: LN2 + fc1 + GELU + fc2 + residuals =============
// 256 threads = 4 waves, each wave owns 64 rows, fully independent (h_sh is
// per-wave) -> ZERO barriers, in-wave lgkmcnt fences only. LN moved inside
// the rt loop and fc2 A-fragments loaded per-kc to cut VGPR (was 200 -> cap
// 2 waves/SIMD; target <=168 -> 3+). Epilogue transposes acc through a f32
// LDS tile so x/xr/out traffic is 32B-vectorized (was 4B scalar).
// xr and out ALIAS (d_out): each (row, col-chunk) is read by the same thread
// that overwrites it, rows disjoint across rt/waves/blocks.
__global__ __launch_bounds__(256, 3) void k_mlp(
    const void* xrv, const void* __restrict__ xg, const short* __restrict__ wb,
    const int* __restrict__ flag, void* outv)
{
  __shared__ __align__(16) short h_sh[4][16][392];   // per-wave 16-row h1 tile

  const int isb = *flag;
  const int wave = threadIdx.x >> 6, lane = threadIdx.x & 63;
  const int quad = lane >> 4, l15 = lane & 15;
  const size_t m0 = (size_t)blockIdx.x * 256 + (size_t)wave * 64;

  // keep LN gamma/beta as bf16 (24 VGPRs, not 48 floats)
  s8v gw[3], gb[3];
  #pragma unroll
  for (int kc = 0; kc < 3; kc++) {
    gw[kc] = ld8(wb + ON2W + kc * 32 + quad * 8);
    gb[kc] = ld8(wb + ON2B + kc * 32 + quad * 8);
  }

  for (int rt = 0; rt < 4; rt++) {
    // ---- LN2 of this tile's 16 rows (row = l15) ----
    size_t ro = (m0 + rt * 16 + l15) * 96;
    float v[3][8]; float sm = 0.f, sq = 0.f;
    #pragma unroll
    for (int kc = 0; kc < 3; kc++) {
      ld8d(xrv, ro + kc * 32 + quad * 8, isb, v[kc]);
      #pragma unroll
      for (int j = 0; j < 8; j++) { sm += v[kc][j]; sq += v[kc][j] * v[kc][j]; }
    }
    sm += __shfl_xor(sm, 16); sm += __shfl_xor(sm, 32);
    sq += __shfl_xor(sq, 16); sq += __shfl_xor(sq, 32);
    float mean = sm * (1.f / 96.f);
    float var  = sq * (1.f / 96.f) - mean * mean;
    float rstd = rsqrtf(var + 1e-5f);
    s8v a2[3];
    #pragma unroll
    for (int kc = 0; kc < 3; kc++) {
      s8v o;
      #pragma unroll
      for (int j = 0; j < 8; j++)
        o[j] = f2bs((v[kc][j] - mean) * rstd * bs2f(gw[kc][j]) + bs2f(gb[kc][j]));
      a2[kc] = o;
    }

    // ---- fc1 + GELU -> h_sh[wave] (C-layout store) ----
    for (int nt = 0; nt < 24; nt++) {
      int col = nt * 16 + l15;
      const short* wrow = wb + OF1W + (size_t)col * 96;
      s8v b0 = ld8(wrow + quad * 8), b1 = ld8(wrow + 32 + quad * 8), b2 = ld8(wrow + 64 + quad * 8);
      float bias = bs2f(wb[OF1B + col]);
      f4v acc = {0.f, 0.f, 0.f, 0.f};
      acc = __builtin_amdgcn_mfma_f32_16x16x32_bf16(a2[0], b0, acc, 0, 0, 0);
      acc = __builtin_amdgcn_mfma_f32_16x16x32_bf16(a2[1], b1, acc, 0, 0, 0);
      acc = __builtin_amdgcn_mfma_f32_16x16x32_bf16(a2[2], b2, acc, 0, 0, 0);
      #pragma unroll
      for (int r = 0; r < 4; r++) {
        float hv = acc[r] + bias;
        hv = 0.5f * hv * (1.f + erff(hv * 0.7071067811865475f));   // exact GELU
        h_sh[wave][quad * 4 + r][col] = f2bs(hv);
      }
    }
    wave_lds_fence();   // h1 visible to own wave's cross-lane reads

    // ---- fc2: A from h_sh (per-kc load), B streamed from L2 ----
    f4v acc6[6];
    #pragma unroll
    for (int nt = 0; nt < 6; nt++) { f4v z = {0.f, 0.f, 0.f, 0.f}; acc6[nt] = z; }
    for (int kc = 0; kc < 12; kc++) {
      s8v ha = *(const s8v*)&h_sh[wave][l15][kc * 32 + quad * 8];
      #pragma unroll
      for (int nt = 0; nt < 6; nt++) {
        s8v b = ld8(wb + OF2W + (size_t)(nt * 16 + l15) * 384 + kc * 32 + quad * 8);
        acc6[nt] = __builtin_amdgcn_mfma_f32_16x16x32_bf16(ha, b, acc6[nt], 0, 0, 0);
      }
    }

    // ---- transpose acc via per-wave f32 LDS tile [16][100] (6400B < slice) ----
    // WAR on h_sh vs the ha reads above: DS pipe in-order per wave.
    float* ot = (float*)&h_sh[wave][0][0];
    #pragma unroll
    for (int nt = 0; nt < 6; nt++) {
      float bias = bs2f(wb[OF2B + nt * 16 + l15]);
      #pragma unroll
      for (int r = 0; r < 4; r++)
        ot[(quad * 4 + r) * 100 + nt * 16 + l15] = acc6[nt][r] + bias;
    }
    wave_lds_fence();   // f32 tile visible for cross-lane vector reads

    // ---- vectorized epilogue: thread (quad,l15) owns row l15, 3 8-col chunks.
    // read-before-write on the aliased xr/out chunk happens in-thread.
    size_t grow = m0 + rt * 16 + l15;
    #pragma unroll
    for (int j = 0; j < 3; j++) {
      int c0 = (quad + 4 * j) * 8;
      float vx[8], vr[8], vo[8];
      ld8d(xg,  grow * 96 + c0, isb, vx);
      ld8d(xrv, grow * 96 + c0, isb, vr);
      #pragma unroll
      for (int e = 0; e < 8; e++) vo[e] = ot[l15 * 100 + c0 + e] + vx[e] + vr[e];
      st8d(outv, grow * 96 + c0, isb, vo);
    }
    // next rt's fc1 ds_writes follow this rt's ot ds_reads in wave order; the
    // read data is consumed before the loop iterates (vo dependency).
  }
}

extern "C" void kernel_launch(void* const* d_in, const int* in_sizes, int n_in,
                              void* d_out, int out_size, void* d_ws, size_t ws_size,
                              hipStream_t stream) {
  int*   flag = (int*)d_ws;
  short* wb   = (short*)d_ws + 8;   // bf16 weight table, byte offset 16

  k_detect_convert<<<64, 256, 0, stream>>>(
      d_in[0],
      d_in[3], d_in[4], d_in[5], d_in[6], d_in[7],
      d_in[1], d_in[2], d_in[8], d_in[9],
      d_in[10], d_in[11], d_in[12], d_in[13],
      flag, wb);
  k_attn_fused<<<32 * 256, 192, 0, stream>>>(d_in[0], wb, flag, d_out);
  k_mlp<<<NTOK / 256, 256, 0, stream>>>(d_out, d_in[0], wb, flag, d_out);
}